// Round 3
// baseline (976.731 us; speedup 1.0000x reference)
//
#include <hip/hip_runtime.h>
#include <hip/hip_bf16.h>

#define HID 512
#define EMB 512
#define KTOP 8
#define BM 64
#define THREADS 512

typedef __attribute__((ext_vector_type(8))) short bf16x8;
typedef __attribute__((ext_vector_type(4))) float f32x4;

__device__ __forceinline__ short f2bf(float f) {
    unsigned u = __builtin_bit_cast(unsigned, f);
    u += 0x7fffu + ((u >> 16) & 1u);          // RNE to bf16
    return (short)(u >> 16);
}
__device__ __forceinline__ float bf2f(short s) {
    unsigned u = ((unsigned)(unsigned short)s) << 16;
    return __builtin_bit_cast(float, u);
}

// Kernel 0: split Wa into bf16 hi/lo, convert Ua to bf16. (1.5 MB in d_ws, L2-resident.)
__global__ void prep_kernel(const float* __restrict__ Wa, const float* __restrict__ Ua,
                            short* __restrict__ wa_hi, short* __restrict__ wa_lo,
                            short* __restrict__ ua_b) {
    int i = blockIdx.x * blockDim.x + threadIdx.x;
    if (i < HID * HID) {
        float w = Wa[i];
        short hi = f2bf(w);
        wa_hi[i] = hi;
        wa_lo[i] = f2bf(w - bf2f(hi));
        ua_b[i]  = f2bf(Ua[i]);
    }
}

// Kernel 1: per-block (64 rows) fused scan + softmax + mt.
// q carried f32 in LDS (XOR-swizzled 16B slots). Scan GEMM = 3-pass split bf16.
// pk GEMM = 1-pass bf16 (one-shot, no error compounding).
__launch_bounds__(THREADS, 2)
__global__ void attn_scan_kernel(const float* __restrict__ query,
                                 const float* __restrict__ topics,
                                 const float* __restrict__ cov,
                                 const short* __restrict__ wa_hi,
                                 const short* __restrict__ wa_lo,
                                 const short* __restrict__ ua_b,
                                 const float* __restrict__ va_w,
                                 const float* __restrict__ va_b,
                                 float* __restrict__ out_mt,
                                 float* __restrict__ out_alpha) {
    __shared__ float q_lds[BM * HID];       // 128 KB, swizzled
    __shared__ float sc_part[4][BM];        // per-N-wave score partials
    __shared__ float scores_s[BM][KTOP];
    __shared__ float alpha_s[BM][KTOP];

    const int tid  = threadIdx.x;
    const int lane = tid & 63;
    const int wave = tid >> 6;      // 0..7
    const int wm   = wave >> 2;     // M wave row: 0..1 (32 rows each)
    const int wn   = wave & 3;      // N wave col: 0..3 (128 cols each)
    const int l15  = lane & 15;
    const int lg   = lane >> 4;
    const long rbase = (long)blockIdx.x * BM;

    // stage query tile -> q_lds (swizzle: 16B slot s at row r stored at s^(r&7))
    for (int i = tid; i < BM * (HID / 4); i += THREADS) {
        int r = i >> 7;
        int c4 = i & 127;
        f32x4 v = *(const f32x4*)(query + (rbase + r) * HID + c4 * 4);
        *(f32x4*)(q_lds + r * HID + ((c4 ^ (r & 7)) << 2)) = v;
    }

    float va_reg[8];
    {
        int cb = wn * 128 + l15;
#pragma unroll
        for (int nf = 0; nf < 8; ++nf) va_reg[nf] = va_w[cb + nf * 16];
    }
    const float vab = va_b[0];
    const int arow0 = wm * 32 + l15;   // local row for mf=0 A-fragments

    __syncthreads();

    for (int step = 0; step < KTOP; ++step) {
        f32x4 accq[2][8];   // q_new accumulator (split-precision, carry)
        f32x4 accp[2][8];   // proj_key accumulator
#pragma unroll
        for (int mf = 0; mf < 2; ++mf)
#pragma unroll
            for (int nf = 0; nf < 8; ++nf) {
                accq[mf][nf] = (f32x4){0.f, 0.f, 0.f, 0.f};
                accp[mf][nf] = (f32x4){0.f, 0.f, 0.f, 0.f};
            }

        const float* tp0 = topics + ((rbase + arow0)      * KTOP + step) * EMB;
        const float* tp1 = topics + ((rbase + arow0 + 16) * KTOP + step) * EMB;

        for (int ch = 0; ch < 16; ++ch) {
            const int k0 = ch * 32 + lg * 8;
            bf16x8 qhi[2], qlo[2], tf[2];
#pragma unroll
            for (int mf = 0; mf < 2; ++mf) {
                const int r = arow0 + mf * 16;
                const float* qp = q_lds + r * HID;
                const int s0 = (((k0 >> 2))     ^ (r & 7)) << 2;
                const int s1 = (((k0 >> 2) + 1) ^ (r & 7)) << 2;
                f32x4 a = *(const f32x4*)(qp + s0);
                f32x4 b = *(const f32x4*)(qp + s1);
#pragma unroll
                for (int j = 0; j < 4; ++j) {
                    short hia = f2bf(a[j]);
                    short hib = f2bf(b[j]);
                    qhi[mf][j]     = hia;
                    qhi[mf][j + 4] = hib;
                    qlo[mf][j]     = f2bf(a[j] - bf2f(hia));
                    qlo[mf][j + 4] = f2bf(b[j] - bf2f(hib));
                }
                const float* tp = mf ? tp1 : tp0;
                f32x4 ta = *(const f32x4*)(tp + k0);
                f32x4 tb = *(const f32x4*)(tp + k0 + 4);
#pragma unroll
                for (int j = 0; j < 4; ++j) {
                    tf[mf][j]     = f2bf(ta[j]);
                    tf[mf][j + 4] = f2bf(tb[j]);
                }
            }
            const int nrow_base = (wn * 128 + l15) * HID + k0;
#pragma unroll
            for (int nf = 0; nf < 8; ++nf) {
                const int off = nrow_base + nf * 16 * HID;
                bf16x8 whi = *(const bf16x8*)(wa_hi + off);
                bf16x8 wlo = *(const bf16x8*)(wa_lo + off);
                bf16x8 ub  = *(const bf16x8*)(ua_b + off);
#pragma unroll
                for (int mf = 0; mf < 2; ++mf) {
                    accq[mf][nf] = __builtin_amdgcn_mfma_f32_16x16x32_bf16(qhi[mf], whi, accq[mf][nf], 0, 0, 0);
                    accq[mf][nf] = __builtin_amdgcn_mfma_f32_16x16x32_bf16(qhi[mf], wlo, accq[mf][nf], 0, 0, 0);
                    accq[mf][nf] = __builtin_amdgcn_mfma_f32_16x16x32_bf16(qlo[mf], whi, accq[mf][nf], 0, 0, 0);
                    accp[mf][nf] = __builtin_amdgcn_mfma_f32_16x16x32_bf16(tf[mf],  ub,  accp[mf][nf], 0, 0, 0);
                }
            }
        }

        // epilogue: s_partial = sum_h tanh(q_new + pk) * va  over this wave's 128 cols
        float part[2][4];
#pragma unroll
        for (int mf = 0; mf < 2; ++mf)
#pragma unroll
            for (int j = 0; j < 4; ++j) part[mf][j] = 0.f;
#pragma unroll
        for (int mf = 0; mf < 2; ++mf)
#pragma unroll
            for (int nf = 0; nf < 8; ++nf)
#pragma unroll
                for (int j = 0; j < 4; ++j) {
                    float x = accq[mf][nf][j] + accp[mf][nf][j];
                    float e = __expf(2.f * x);
                    float th = 1.f - 2.f / (e + 1.f);   // tanh(x)
                    part[mf][j] += th * va_reg[nf];
                }
#pragma unroll
        for (int m = 8; m >= 1; m >>= 1)
#pragma unroll
            for (int mf = 0; mf < 2; ++mf)
#pragma unroll
                for (int j = 0; j < 4; ++j)
                    part[mf][j] += __shfl_xor(part[mf][j], m, 64);

        __syncthreads();   // all q_lds reads for this step complete

        // write q_new (f32, swizzled) — C/D layout: row=4*lg+j, col=l15 per frag
#pragma unroll
        for (int mf = 0; mf < 2; ++mf)
#pragma unroll
            for (int nf = 0; nf < 8; ++nf)
#pragma unroll
                for (int j = 0; j < 4; ++j) {
                    int r = wm * 32 + mf * 16 + lg * 4 + j;
                    int h = wn * 128 + nf * 16 + l15;
                    q_lds[r * HID + ((((h >> 2) ^ (r & 7)) << 2) | (h & 3))] = accq[mf][nf][j];
                }
        if (l15 == 0) {
#pragma unroll
            for (int mf = 0; mf < 2; ++mf)
#pragma unroll
                for (int j = 0; j < 4; ++j)
                    sc_part[wn][wm * 32 + mf * 16 + lg * 4 + j] = part[mf][j];
        }
        __syncthreads();   // q_new + sc_part visible

        if (tid < BM) {
            float s = sc_part[0][tid] + sc_part[1][tid] + sc_part[2][tid] + sc_part[3][tid] + vab;
            scores_s[tid][step] = s * cov[(rbase + tid) * KTOP + step];
        }
    }

    __syncthreads();
    // softmax over K per row
    if (tid < BM) {
        float mx = scores_s[tid][0];
#pragma unroll
        for (int k = 1; k < KTOP; ++k) mx = fmaxf(mx, scores_s[tid][k]);
        float e[KTOP], sum = 0.f;
#pragma unroll
        for (int k = 0; k < KTOP; ++k) { e[k] = __expf(scores_s[tid][k] - mx); sum += e[k]; }
#pragma unroll
        for (int k = 0; k < KTOP; ++k) {
            float a = e[k] / sum;
            alpha_s[tid][k] = a;
            out_alpha[(rbase + tid) * KTOP + k] = a;
        }
    }
    __syncthreads();

    // mt = sum_k alpha_k * topics[:,k,:]  (streaming, coalesced float4)
    for (int i = tid; i < BM * (EMB / 4); i += THREADS) {
        int r = i >> 7;
        int c4 = i & 127;
        const float* tb = topics + (rbase + r) * KTOP * EMB + c4 * 4;
        f32x4 acc = {0.f, 0.f, 0.f, 0.f};
#pragma unroll
        for (int k = 0; k < KTOP; ++k) {
            f32x4 t = *(const f32x4*)(tb + k * EMB);
            float a = alpha_s[r][k];
            acc[0] += t[0] * a;
            acc[1] += t[1] * a;
            acc[2] += t[2] * a;
            acc[3] += t[3] * a;
        }
        *(f32x4*)(out_mt + (rbase + r) * EMB + c4 * 4) = acc;
    }
}

extern "C" void kernel_launch(void* const* d_in, const int* in_sizes, int n_in,
                              void* d_out, int out_size, void* d_ws, size_t ws_size,
                              hipStream_t stream) {
    const float* query  = (const float*)d_in[0];
    const float* topics = (const float*)d_in[1];
    const float* cov    = (const float*)d_in[2];
    const float* Ua     = (const float*)d_in[3];
    const float* Wa     = (const float*)d_in[4];
    const float* va     = (const float*)d_in[5];
    const float* vab    = (const float*)d_in[6];

    const int Brows = in_sizes[0] / HID;   // 16384

    short* wa_hi = (short*)d_ws;
    short* wa_lo = wa_hi + HID * HID;
    short* ua_b  = wa_lo + HID * HID;

    float* out_mt    = (float*)d_out;
    float* out_alpha = out_mt + (size_t)Brows * EMB;

    prep_kernel<<<(HID * HID + 255) / 256, 256, 0, stream>>>(Wa, Ua, wa_hi, wa_lo, ua_b);
    attn_scan_kernel<<<Brows / BM, THREADS, 0, stream>>>(query, topics, cov,
                                                         wa_hi, wa_lo, ua_b,
                                                         va, vab, out_mt, out_alpha);
}